// Round 1
// baseline (5149.279 us; speedup 1.0000x reference)
//
#include <hip/hip_runtime.h>

typedef __attribute__((ext_vector_type(8))) short short8;
typedef __attribute__((ext_vector_type(4))) float f32x4;
typedef __attribute__((ext_vector_type(4))) unsigned short ushort4_t;
typedef __attribute__((ext_vector_type(4))) float float4_t;

#define DEVI static __device__ __forceinline__

DEVI unsigned short f2b(float f){
    unsigned int u = __float_as_uint(f);
    u += 0x7fffu + ((u >> 16) & 1u);
    return (unsigned short)(u >> 16);
}
DEVI float b2f(unsigned short h){ return __uint_as_float(((unsigned int)h) << 16); }

DEVI float sigm(float x){
    float e = __expf(-x);
    return __builtin_amdgcn_rcpf(1.f + e);
}
DEVI float tanh_(float x){
    float e = __expf(2.f * x);              // overflow -> inf -> rcp -> 0 -> tanh=1 (graceful)
    return 1.f - 2.f * __builtin_amdgcn_rcpf(1.f + e);
}

// ---------------------------------------------------------------------------
// Weight cast f32 -> bf16 into wbuf segments
// ---------------------------------------------------------------------------
struct CastArgs { const float* s[10]; };

__global__ __launch_bounds__(256, 4) void cast_w(CastArgs ca, unsigned short* __restrict__ wbuf){
    const int off[10] = {0,196608,393216,589824,786432,1179648,1376256,1769472,1966080,2097152};
    const int cnt[10] = {196608,196608,196608,196608,393216,196608,393216,196608,131072,131072};
    int seg = blockIdx.y;
    const float* s = ca.s[seg];
    unsigned short* d = wbuf + off[seg];
    int n = cnt[seg];
    for (int i = (blockIdx.x * 256 + threadIdx.x) * 4; i < n; i += 192 * 256 * 4){
        float4_t v = *(const float4_t*)&s[i];
        ushort4_t o;
        o[0] = f2b(v[0]); o[1] = f2b(v[1]); o[2] = f2b(v[2]); o[3] = f2b(v[3]);
        *(ushort4_t*)&d[i] = o;
    }
}

// ---------------------------------------------------------------------------
// x (B,C,L) f32  ->  xT (B, L, C) bf16
// ---------------------------------------------------------------------------
__global__ __launch_bounds__(256, 4) void transpose_x(const float* __restrict__ x, unsigned short* __restrict__ xT){
    __shared__ float tile[32][33];
    int t0 = blockIdx.x * 32, c0 = blockIdx.y * 32, b = blockIdx.z;
    int tid = threadIdx.x;
    int r  = tid >> 3;          // 0..31
    int jc = (tid & 7) * 4;     // 0..28
    float4_t v = *(const float4_t*)&x[(size_t)b * 524288 + (size_t)(c0 + r) * 2048 + t0 + jc];
    tile[r][jc + 0] = v[0]; tile[r][jc + 1] = v[1]; tile[r][jc + 2] = v[2]; tile[r][jc + 3] = v[3];
    __syncthreads();
    int rt = tid >> 3;          // t row 0..31
    int cc = (tid & 7) * 4;     // c 0..28
    ushort4_t o;
    o[0] = f2b(tile[cc + 0][rt]);
    o[1] = f2b(tile[cc + 1][rt]);
    o[2] = f2b(tile[cc + 2][rt]);
    o[3] = f2b(tile[cc + 3][rt]);
    *(ushort4_t*)&xT[((size_t)b * 2048 + t0 + rt) * 256 + c0 + cc] = o;
}

// ---------------------------------------------------------------------------
// GEMM: C[M][N] = A[M][K] @ Bw[N][K]^T + bias1 (+bias2 if col<bias2_lim), bf16 out
// 64x64 tile, 4 waves, MFMA 16x16x32 bf16
// ---------------------------------------------------------------------------
template<int RELU>
__global__ __launch_bounds__(256, 4) void gemm64(
    const unsigned short* __restrict__ A, const unsigned short* __restrict__ Bw,
    const float* __restrict__ bias1, const float* __restrict__ bias2, int bias2_lim,
    unsigned short* __restrict__ Cout, int K, int N)
{
    __shared__ unsigned short As[64][72];
    __shared__ unsigned short Bs[64][72];
    int m0 = blockIdx.x * 64, n0 = blockIdx.y * 64;
    int tid = threadIdx.x, lane = tid & 63, w = tid >> 6;
    int l15 = lane & 15, kq = lane >> 4;
    int lr = tid >> 2, lc = (tid & 3) * 16;
    f32x4 acc[4];
#pragma unroll
    for (int n = 0; n < 4; ++n) acc[n] = (f32x4){0.f, 0.f, 0.f, 0.f};

    for (int kt = 0; kt < K; kt += 64){
        short8 a0 = *(const short8*)&A[(size_t)(m0 + lr) * K + kt + lc];
        short8 a1 = *(const short8*)&A[(size_t)(m0 + lr) * K + kt + lc + 8];
        short8 b0 = *(const short8*)&Bw[(size_t)(n0 + lr) * K + kt + lc];
        short8 b1 = *(const short8*)&Bw[(size_t)(n0 + lr) * K + kt + lc + 8];
        __syncthreads();
        *(short8*)&As[lr][lc]     = a0;
        *(short8*)&As[lr][lc + 8] = a1;
        *(short8*)&Bs[lr][lc]     = b0;
        *(short8*)&Bs[lr][lc + 8] = b1;
        __syncthreads();
#pragma unroll
        for (int kc = 0; kc < 2; ++kc){
            short8 af = *(const short8*)&As[w * 16 + l15][kc * 32 + kq * 8];
#pragma unroll
            for (int n = 0; n < 4; ++n){
                short8 bfv = *(const short8*)&Bs[n * 16 + l15][kc * 32 + kq * 8];
                acc[n] = __builtin_amdgcn_mfma_f32_16x16x32_bf16(af, bfv, acc[n], 0, 0, 0);
            }
        }
    }
#pragma unroll
    for (int n = 0; n < 4; ++n){
        int col = n0 + n * 16 + l15;
        float bs = bias1 ? bias1[col] : 0.f;
        if (bias2 && col < bias2_lim) bs += bias2[col];
#pragma unroll
        for (int r = 0; r < 4; ++r){
            int row = m0 + w * 16 + kq * 4 + r;
            float v = acc[n][r] + bs;
            if (RELU) v = fmaxf(v, 0.f);
            Cout[(size_t)row * N + col] = f2b(v);
        }
    }
}

// ---------------------------------------------------------------------------
// Final FFN GEMM with f32 output written TRANSPOSED to (B,C,L):
// out[b][col][t] = A[row=b*2048+t] @ w2^T + b2
// ---------------------------------------------------------------------------
__global__ __launch_bounds__(256, 4) void gemm64_tr(
    const unsigned short* __restrict__ A, const unsigned short* __restrict__ Bw,
    const float* __restrict__ bias, float* __restrict__ Out, int K, int N)
{
    __shared__ unsigned short As[64][72];
    __shared__ unsigned short Bs[64][72];
    int m0 = blockIdx.x * 64, n0 = blockIdx.y * 64;
    int tid = threadIdx.x, lane = tid & 63, w = tid >> 6;
    int l15 = lane & 15, kq = lane >> 4;
    int lr = tid >> 2, lc = (tid & 3) * 16;
    f32x4 acc[4];
#pragma unroll
    for (int n = 0; n < 4; ++n) acc[n] = (f32x4){0.f, 0.f, 0.f, 0.f};

    for (int kt = 0; kt < K; kt += 64){
        short8 a0 = *(const short8*)&A[(size_t)(m0 + lr) * K + kt + lc];
        short8 a1 = *(const short8*)&A[(size_t)(m0 + lr) * K + kt + lc + 8];
        short8 b0 = *(const short8*)&Bw[(size_t)(n0 + lr) * K + kt + lc];
        short8 b1 = *(const short8*)&Bw[(size_t)(n0 + lr) * K + kt + lc + 8];
        __syncthreads();
        *(short8*)&As[lr][lc]     = a0;
        *(short8*)&As[lr][lc + 8] = a1;
        *(short8*)&Bs[lr][lc]     = b0;
        *(short8*)&Bs[lr][lc + 8] = b1;
        __syncthreads();
#pragma unroll
        for (int kc = 0; kc < 2; ++kc){
            short8 af = *(const short8*)&As[w * 16 + l15][kc * 32 + kq * 8];
#pragma unroll
            for (int n = 0; n < 4; ++n){
                short8 bfv = *(const short8*)&Bs[n * 16 + l15][kc * 32 + kq * 8];
                acc[n] = __builtin_amdgcn_mfma_f32_16x16x32_bf16(af, bfv, acc[n], 0, 0, 0);
            }
        }
    }
    int m_base = m0 + w * 16 + kq * 4;
    int bidx = m_base >> 11;
    int t0 = m_base & 2047;
#pragma unroll
    for (int n = 0; n < 4; ++n){
        int col = n0 + n * 16 + l15;
        float bs = bias[col];
        float4_t o = (float4_t){acc[n][0] + bs, acc[n][1] + bs, acc[n][2] + bs, acc[n][3] + bs};
        *(float4_t*)&Out[(size_t)bidx * 524288 + (size_t)col * 2048 + t0] = o;
    }
}

// ---------------------------------------------------------------------------
// GRU scan: one workgroup per (dir, batch) chain. 8 waves (512 thr).
// gi: [2][16][2048][768] bf16 (b_ih + b_hh(r,z) pre-folded)
// Each wave owns h-cols [32w, 32w+32): 3 gates x 2 ntiles x 8 kchunks of W_hh
// held in VGPRs (192 regs). M=1 MFMA: all A rows replicated -> every lane
// holds the same gate value, no divergence in the nonlinearity.
// ---------------------------------------------------------------------------
__global__ __launch_bounds__(512, 2) void gru_scan(
    const unsigned short* __restrict__ gi,
    const unsigned short* __restrict__ whh_f, const unsigned short* __restrict__ whh_b,
    const float* __restrict__ bhh_f, const float* __restrict__ bhh_b,
    unsigned short* __restrict__ outp, int out_stride, size_t out_dir_off)
{
    const int T = 2048;
    int b = blockIdx.x & 15, dir = blockIdx.x >> 4;
    const unsigned short* giP = gi + ((size_t)(dir * 16 + b)) * T * 768;
    const unsigned short* wP  = dir ? whh_b : whh_f;
    const float* bhP          = dir ? bhh_b : bhh_f;
    unsigned short* oP        = outp + out_dir_off * (size_t)dir;

    int tid = threadIdx.x, lane = tid & 63, w = tid >> 6;
    int l15 = lane & 15, kq = lane >> 4;
    int hc0 = w * 32;

    // persistent W_hh fragments
    short8 bf[3][2][8];
#pragma unroll
    for (int g = 0; g < 3; ++g)
#pragma unroll
        for (int n = 0; n < 2; ++n)
#pragma unroll
            for (int kc = 0; kc < 8; ++kc){
                int col = g * 256 + hc0 + n * 16 + l15;
                bf[g][n][kc] = *(const short8*)&wP[(size_t)col * 256 + kc * 32 + kq * 8];
            }
    float bhn[2] = { bhP[512 + hc0 + l15], bhP[512 + hc0 + 16 + l15] };

    __shared__ unsigned short hbuf[2][256];
    __shared__ unsigned short gibuf[2][768];

    int tt0 = dir ? (T - 1) : 0;
    if (tid < 256) hbuf[0][tid] = 0;
    gibuf[0][tid] = giP[(size_t)tt0 * 768 + tid];
    if (tid < 256) gibuf[0][512 + tid] = giP[(size_t)tt0 * 768 + 512 + tid];
    __syncthreads();

    float hold[2] = {0.f, 0.f};
    int cur = 0;
#pragma clang loop unroll(disable)
    for (int t = 0; t < T; ++t){
        int tt = dir ? (T - 1 - t) : t;
        int tn = (t + 1 < T) ? (dir ? (T - 2 - t) : (t + 1)) : tt;

        // prefetch next step's gi row into registers (hidden under MFMAs)
        unsigned short g0 = giP[(size_t)tn * 768 + tid];
        unsigned short g1 = 0;
        if (tid < 256) g1 = giP[(size_t)tn * 768 + 512 + tid];

        f32x4 acc[3][2];
#pragma unroll
        for (int g = 0; g < 3; ++g)
#pragma unroll
            for (int n = 0; n < 2; ++n)
                acc[g][n] = (f32x4){0.f, 0.f, 0.f, 0.f};

        short8 acur = *(const short8*)&hbuf[cur][kq * 8];
#pragma unroll
        for (int kc = 0; kc < 8; ++kc){
            short8 anxt = acur;
            if (kc < 7) anxt = *(const short8*)&hbuf[cur][(kc + 1) * 32 + kq * 8];
#pragma unroll
            for (int g = 0; g < 3; ++g)
#pragma unroll
                for (int n = 0; n < 2; ++n)
                    acc[g][n] = __builtin_amdgcn_mfma_f32_16x16x32_bf16(acur, bf[g][n][kc], acc[g][n], 0, 0, 0);
            acur = anxt;
        }

        int nxt = cur ^ 1;
#pragma unroll
        for (int n = 0; n < 2; ++n){
            int c = hc0 + n * 16 + l15;
            float gir = b2f(gibuf[cur][c]);
            float giz = b2f(gibuf[cur][256 + c]);
            float gin = b2f(gibuf[cur][512 + c]);
            float rr = sigm(gir + acc[0][n][0]);
            float zz = sigm(giz + acc[1][n][0]);
            float nn = tanh_(gin + rr * (acc[2][n][0] + bhn[n]));
            float hv = nn + zz * (hold[n] - nn);
            hold[n] = hv;
            if (kq == 0){
                unsigned short hb = f2b(hv);
                hbuf[nxt][c] = hb;
                oP[(size_t)(b * T + tt) * out_stride + c] = hb;
            }
        }
        gibuf[nxt][tid] = g0;
        if (tid < 256) gibuf[nxt][512 + tid] = g1;
        __syncthreads();
        cur = nxt;
    }
}

// ---------------------------------------------------------------------------
// sum(fwd,bwd) + LayerNorm -> bf16 rows
// ---------------------------------------------------------------------------
__global__ __launch_bounds__(256, 4) void sum_ln(
    const unsigned short* __restrict__ h1, const float* __restrict__ g,
    const float* __restrict__ bb, unsigned short* __restrict__ vn)
{
    int row = blockIdx.x * 4 + (threadIdx.x >> 6);
    int lane = threadIdx.x & 63;
    ushort4_t fa = *(const ushort4_t*)&h1[(size_t)row * 256 + lane * 4];
    ushort4_t ba = *(const ushort4_t*)&h1[8388608 + (size_t)row * 256 + lane * 4];
    float v[4]; float s = 0.f, q = 0.f;
#pragma unroll
    for (int k = 0; k < 4; ++k){
        v[k] = b2f(fa[k]) + b2f(ba[k]);
        s += v[k]; q += v[k] * v[k];
    }
#pragma unroll
    for (int o = 32; o; o >>= 1){
        s += __shfl_xor(s, o);
        q += __shfl_xor(q, o);
    }
    float mu = s * (1.f / 256.f);
    float var = q * (1.f / 256.f) - mu * mu;
    float rs = rsqrtf(var + 1e-5f);
    float4_t gg = *(const float4_t*)&g[lane * 4];
    float4_t bv = *(const float4_t*)&bb[lane * 4];
    ushort4_t o4;
#pragma unroll
    for (int k = 0; k < 4; ++k) o4[k] = f2b((v[k] - mu) * rs * gg[k] + bv[k]);
    *(ushort4_t*)&vn[(size_t)row * 256 + lane * 4] = o4;
}

// ---------------------------------------------------------------------------
extern "C" void kernel_launch(void* const* d_in, const int* in_sizes, int n_in,
                              void* d_out, int out_size, void* d_ws, size_t ws_size,
                              hipStream_t stream)
{
    (void)in_sizes; (void)n_in; (void)out_size; (void)ws_size;
    const float* x = (const float*)d_in[0];

    char* ws = (char*)d_ws;
    unsigned short* xT   = (unsigned short*)(ws);                 // 16 MB   (later reused as vn)
    unsigned short* giA  = (unsigned short*)(ws + 16777216);      // 100.7MB (gi0 -> gi1 -> hid)
    unsigned short* h0   = (unsigned short*)(ws + 117440512);     // 33.6 MB (h0out -> h1out)
    unsigned short* wbuf = (unsigned short*)(ws + 150994944);     // 4.5 MB bf16 weights
    float* out = (float*)d_out;

    // 1) cast weights to bf16
    CastArgs ca;
    ca.s[0] = (const float*)d_in[1];   // w_ih0f
    ca.s[1] = (const float*)d_in[2];   // w_hh0f
    ca.s[2] = (const float*)d_in[5];   // w_ih0b
    ca.s[3] = (const float*)d_in[6];   // w_hh0b
    ca.s[4] = (const float*)d_in[9];   // w_ih1f
    ca.s[5] = (const float*)d_in[10];  // w_hh1f
    ca.s[6] = (const float*)d_in[13];  // w_ih1b
    ca.s[7] = (const float*)d_in[14];  // w_hh1b
    ca.s[8] = (const float*)d_in[19];  // w1
    ca.s[9] = (const float*)d_in[21];  // w2
    cast_w<<<dim3(192, 10), 256, 0, stream>>>(ca, wbuf);

    // 2) transpose x -> xT bf16
    transpose_x<<<dim3(64, 8, 16), 256, 0, stream>>>(x, xT);

    // 3) layer-0 input gates: gi0[dir] = xT @ w_ih0d^T + b_ih0d + b_hh0d(r,z)
    gemm64<0><<<dim3(512, 12), 256, 0, stream>>>(xT, wbuf + 0,
        (const float*)d_in[3], (const float*)d_in[4], 512, giA, 256, 768);
    gemm64<0><<<dim3(512, 12), 256, 0, stream>>>(xT, wbuf + 393216,
        (const float*)d_in[7], (const float*)d_in[8], 512, giA + (size_t)25165824, 256, 768);

    // 4) layer-0 scan -> h0 [32768][512] (fwd cols 0-255, bwd 256-511)
    gru_scan<<<32, 512, 0, stream>>>(giA, wbuf + 196608, wbuf + 589824,
        (const float*)d_in[4], (const float*)d_in[8], h0, 512, (size_t)256);

    // 5) layer-1 input gates from h0 (K=512)
    gemm64<0><<<dim3(512, 12), 256, 0, stream>>>(h0, wbuf + 786432,
        (const float*)d_in[11], (const float*)d_in[12], 512, giA, 512, 768);
    gemm64<0><<<dim3(512, 12), 256, 0, stream>>>(h0, wbuf + 1376256,
        (const float*)d_in[15], (const float*)d_in[16], 512, giA + (size_t)25165824, 512, 768);

    // 6) layer-1 scan -> h0 reused as h1out [2][32768][256]
    gru_scan<<<32, 512, 0, stream>>>(giA, wbuf + 1179648, wbuf + 1769472,
        (const float*)d_in[12], (const float*)d_in[16], h0, 256, (size_t)8388608);

    // 7) sum dirs + LayerNorm -> vn (reuse xT)
    sum_ln<<<8192, 256, 0, stream>>>(h0, (const float*)d_in[17], (const float*)d_in[18], xT);

    // 8) FFN1: relu(vn @ w1^T + b1) -> hid (reuse giA)
    gemm64<1><<<dim3(512, 8), 256, 0, stream>>>(xT, wbuf + 1966080,
        (const float*)d_in[20], nullptr, 0, giA, 256, 512);

    // 9) FFN2: hid @ w2^T + b2 -> d_out f32, transposed to (B,C,L)
    gemm64_tr<<<dim3(512, 4), 256, 0, stream>>>(giA, wbuf + 2097152,
        (const float*)d_in[22], out, 512, 256);
}

// Round 2
// 4328.182 us; speedup vs baseline: 1.1897x; 1.1897x over previous
//
#include <hip/hip_runtime.h>

typedef __attribute__((ext_vector_type(8))) short short8;
typedef __attribute__((ext_vector_type(4))) float f32x4;
typedef __attribute__((ext_vector_type(4))) unsigned short ushort4_t;
typedef __attribute__((ext_vector_type(4))) float float4_t;

#define DEVI static __device__ __forceinline__

DEVI unsigned short f2b(float f){
    unsigned int u = __float_as_uint(f);
    u += 0x7fffu + ((u >> 16) & 1u);
    return (unsigned short)(u >> 16);
}
DEVI float b2f(unsigned short h){ return __uint_as_float(((unsigned int)h) << 16); }

DEVI float sigm(float x){
    float e = __expf(-x);
    return __builtin_amdgcn_rcpf(1.f + e);
}
DEVI float tanh_(float x){
    float e = __expf(2.f * x);              // overflow -> inf -> rcp -> 0 -> tanh=1 (graceful)
    return 1.f - 2.f * __builtin_amdgcn_rcpf(1.f + e);
}

// ---------------------------------------------------------------------------
// Weight cast f32 -> bf16 into wbuf segments
// ---------------------------------------------------------------------------
struct CastArgs { const float* s[10]; };

__global__ __launch_bounds__(256, 4) void cast_w(CastArgs ca, unsigned short* __restrict__ wbuf){
    const int off[10] = {0,196608,393216,589824,786432,1179648,1376256,1769472,1966080,2097152};
    const int cnt[10] = {196608,196608,196608,196608,393216,196608,393216,196608,131072,131072};
    int seg = blockIdx.y;
    const float* s = ca.s[seg];
    unsigned short* d = wbuf + off[seg];
    int n = cnt[seg];
    for (int i = (blockIdx.x * 256 + threadIdx.x) * 4; i < n; i += 192 * 256 * 4){
        float4_t v = *(const float4_t*)&s[i];
        ushort4_t o;
        o[0] = f2b(v[0]); o[1] = f2b(v[1]); o[2] = f2b(v[2]); o[3] = f2b(v[3]);
        *(ushort4_t*)&d[i] = o;
    }
}

// ---------------------------------------------------------------------------
// x (B,C,L) f32  ->  xT (B, L, C) bf16
// ---------------------------------------------------------------------------
__global__ __launch_bounds__(256, 4) void transpose_x(const float* __restrict__ x, unsigned short* __restrict__ xT){
    __shared__ float tile[32][33];
    int t0 = blockIdx.x * 32, c0 = blockIdx.y * 32, b = blockIdx.z;
    int tid = threadIdx.x;
    int r  = tid >> 3;          // 0..31
    int jc = (tid & 7) * 4;     // 0..28
    float4_t v = *(const float4_t*)&x[(size_t)b * 524288 + (size_t)(c0 + r) * 2048 + t0 + jc];
    tile[r][jc + 0] = v[0]; tile[r][jc + 1] = v[1]; tile[r][jc + 2] = v[2]; tile[r][jc + 3] = v[3];
    __syncthreads();
    int rt = tid >> 3;          // t row 0..31
    int cc = (tid & 7) * 4;     // c 0..28
    ushort4_t o;
    o[0] = f2b(tile[cc + 0][rt]);
    o[1] = f2b(tile[cc + 1][rt]);
    o[2] = f2b(tile[cc + 2][rt]);
    o[3] = f2b(tile[cc + 3][rt]);
    *(ushort4_t*)&xT[((size_t)b * 2048 + t0 + rt) * 256 + c0 + cc] = o;
}

// ---------------------------------------------------------------------------
// GEMM: C[M][N] = A[M][K] @ Bw[N][K]^T + bias1 (+bias2 if col<bias2_lim), bf16 out
// 64x64 tile, 4 waves, MFMA 16x16x32 bf16
// ---------------------------------------------------------------------------
template<int RELU>
__global__ __launch_bounds__(256, 4) void gemm64(
    const unsigned short* __restrict__ A, const unsigned short* __restrict__ Bw,
    const float* __restrict__ bias1, const float* __restrict__ bias2, int bias2_lim,
    unsigned short* __restrict__ Cout, int K, int N)
{
    __shared__ unsigned short As[64][72];
    __shared__ unsigned short Bs[64][72];
    int m0 = blockIdx.x * 64, n0 = blockIdx.y * 64;
    int tid = threadIdx.x, lane = tid & 63, w = tid >> 6;
    int l15 = lane & 15, kq = lane >> 4;
    int lr = tid >> 2, lc = (tid & 3) * 16;
    f32x4 acc[4];
#pragma unroll
    for (int n = 0; n < 4; ++n) acc[n] = (f32x4){0.f, 0.f, 0.f, 0.f};

    for (int kt = 0; kt < K; kt += 64){
        short8 a0 = *(const short8*)&A[(size_t)(m0 + lr) * K + kt + lc];
        short8 a1 = *(const short8*)&A[(size_t)(m0 + lr) * K + kt + lc + 8];
        short8 b0 = *(const short8*)&Bw[(size_t)(n0 + lr) * K + kt + lc];
        short8 b1 = *(const short8*)&Bw[(size_t)(n0 + lr) * K + kt + lc + 8];
        __syncthreads();
        *(short8*)&As[lr][lc]     = a0;
        *(short8*)&As[lr][lc + 8] = a1;
        *(short8*)&Bs[lr][lc]     = b0;
        *(short8*)&Bs[lr][lc + 8] = b1;
        __syncthreads();
#pragma unroll
        for (int kc = 0; kc < 2; ++kc){
            short8 af = *(const short8*)&As[w * 16 + l15][kc * 32 + kq * 8];
#pragma unroll
            for (int n = 0; n < 4; ++n){
                short8 bfv = *(const short8*)&Bs[n * 16 + l15][kc * 32 + kq * 8];
                acc[n] = __builtin_amdgcn_mfma_f32_16x16x32_bf16(af, bfv, acc[n], 0, 0, 0);
            }
        }
    }
#pragma unroll
    for (int n = 0; n < 4; ++n){
        int col = n0 + n * 16 + l15;
        float bs = bias1 ? bias1[col] : 0.f;
        if (bias2 && col < bias2_lim) bs += bias2[col];
#pragma unroll
        for (int r = 0; r < 4; ++r){
            int row = m0 + w * 16 + kq * 4 + r;
            float v = acc[n][r] + bs;
            if (RELU) v = fmaxf(v, 0.f);
            Cout[(size_t)row * N + col] = f2b(v);
        }
    }
}

// ---------------------------------------------------------------------------
// Final FFN GEMM with f32 output written TRANSPOSED to (B,C,L):
// out[b][col][t] = A[row=b*2048+t] @ w2^T + b2
// ---------------------------------------------------------------------------
__global__ __launch_bounds__(256, 4) void gemm64_tr(
    const unsigned short* __restrict__ A, const unsigned short* __restrict__ Bw,
    const float* __restrict__ bias, float* __restrict__ Out, int K, int N)
{
    __shared__ unsigned short As[64][72];
    __shared__ unsigned short Bs[64][72];
    int m0 = blockIdx.x * 64, n0 = blockIdx.y * 64;
    int tid = threadIdx.x, lane = tid & 63, w = tid >> 6;
    int l15 = lane & 15, kq = lane >> 4;
    int lr = tid >> 2, lc = (tid & 3) * 16;
    f32x4 acc[4];
#pragma unroll
    for (int n = 0; n < 4; ++n) acc[n] = (f32x4){0.f, 0.f, 0.f, 0.f};

    for (int kt = 0; kt < K; kt += 64){
        short8 a0 = *(const short8*)&A[(size_t)(m0 + lr) * K + kt + lc];
        short8 a1 = *(const short8*)&A[(size_t)(m0 + lr) * K + kt + lc + 8];
        short8 b0 = *(const short8*)&Bw[(size_t)(n0 + lr) * K + kt + lc];
        short8 b1 = *(const short8*)&Bw[(size_t)(n0 + lr) * K + kt + lc + 8];
        __syncthreads();
        *(short8*)&As[lr][lc]     = a0;
        *(short8*)&As[lr][lc + 8] = a1;
        *(short8*)&Bs[lr][lc]     = b0;
        *(short8*)&Bs[lr][lc + 8] = b1;
        __syncthreads();
#pragma unroll
        for (int kc = 0; kc < 2; ++kc){
            short8 af = *(const short8*)&As[w * 16 + l15][kc * 32 + kq * 8];
#pragma unroll
            for (int n = 0; n < 4; ++n){
                short8 bfv = *(const short8*)&Bs[n * 16 + l15][kc * 32 + kq * 8];
                acc[n] = __builtin_amdgcn_mfma_f32_16x16x32_bf16(af, bfv, acc[n], 0, 0, 0);
            }
        }
    }
    int m_base = m0 + w * 16 + kq * 4;
    int bidx = m_base >> 11;
    int t0 = m_base & 2047;
#pragma unroll
    for (int n = 0; n < 4; ++n){
        int col = n0 + n * 16 + l15;
        float bs = bias[col];
        float4_t o = (float4_t){acc[n][0] + bs, acc[n][1] + bs, acc[n][2] + bs, acc[n][3] + bs};
        *(float4_t*)&Out[(size_t)bidx * 524288 + (size_t)col * 2048 + t0] = o;
    }
}

// ---------------------------------------------------------------------------
// GRU scan: one workgroup per (dir, batch) chain. 8 waves (512 thr).
// gi: [2][16][2048][768] bf16 (b_ih + b_hh(r,z) pre-folded)
// Each wave owns h-cols [32w, 32w+32): 3 gates x 2 ntiles x 8 kchunks of W_hh
// pinned in VGPRs (192 regs) via asm opacity barrier so the compiler cannot
// rematerialize the loads inside the loop. gi is read per-lane (6 scalars),
// prefetched one step ahead; no gi LDS staging.
// ---------------------------------------------------------------------------
__global__ __launch_bounds__(512, 2) void gru_scan(
    const unsigned short* __restrict__ gi,
    const unsigned short* __restrict__ whh_f, const unsigned short* __restrict__ whh_b,
    const float* __restrict__ bhh_f, const float* __restrict__ bhh_b,
    unsigned short* __restrict__ outp, int out_stride, size_t out_dir_off)
{
    const int T = 2048;
    int b = blockIdx.x & 15, dir = blockIdx.x >> 4;
    const unsigned short* giP = gi + ((size_t)(dir * 16 + b)) * T * 768;
    const unsigned short* wP  = dir ? whh_b : whh_f;
    const float* bhP          = dir ? bhh_b : bhh_f;
    unsigned short* oP        = outp + out_dir_off * (size_t)dir;

    int tid = threadIdx.x, lane = tid & 63, w = tid >> 6;
    int l15 = lane & 15, kq = lane >> 4;
    int hc0 = w * 32;

    // persistent W_hh fragments, pinned in registers
    short8 bf[3][2][8];
#pragma unroll
    for (int g = 0; g < 3; ++g)
#pragma unroll
        for (int n = 0; n < 2; ++n)
#pragma unroll
            for (int kc = 0; kc < 8; ++kc){
                int col = g * 256 + hc0 + n * 16 + l15;
                bf[g][n][kc] = *(const short8*)&wP[(size_t)col * 256 + kc * 32 + kq * 8];
            }
#pragma unroll
    for (int g = 0; g < 3; ++g)
#pragma unroll
        for (int n = 0; n < 2; ++n)
#pragma unroll
            for (int kc = 0; kc < 8; ++kc)
                asm volatile("" : "+v"(bf[g][n][kc]));

    float bhn[2] = { bhP[512 + hc0 + l15], bhP[512 + hc0 + 16 + l15] };

    __shared__ unsigned short hbuf[2][256];
    if (tid < 256) hbuf[0][tid] = 0;

    // per-lane gi columns
    int c0 = hc0 + l15, c1 = hc0 + 16 + l15;
    int tt0 = dir ? (T - 1) : 0;
    int tstep = dir ? -1 : 1;

    // prefetch gi for t=0
    const unsigned short* gR = giP + (size_t)tt0 * 768;
    unsigned short ur0 = gR[c0],       ur1 = gR[c1];
    unsigned short uz0 = gR[256 + c0], uz1 = gR[256 + c1];
    unsigned short un0 = gR[512 + c0], un1 = gR[512 + c1];
    __syncthreads();

    float hold[2] = {0.f, 0.f};
    int cur = 0;
    int tt = tt0;
#pragma clang loop unroll(disable)
    for (int t = 0; t < T; ++t){
        int tn = (t + 1 < T) ? (tt + tstep) : tt;
        const unsigned short* gN = giP + (size_t)tn * 768;
        // prefetch next step's gi scalars (hidden under MFMAs)
        unsigned short vr0 = gN[c0],       vr1 = gN[c1];
        unsigned short vz0 = gN[256 + c0], vz1 = gN[256 + c1];
        unsigned short vn0 = gN[512 + c0], vn1 = gN[512 + c1];

        f32x4 acc[3][2];
#pragma unroll
        for (int g = 0; g < 3; ++g)
#pragma unroll
            for (int n = 0; n < 2; ++n)
                acc[g][n] = (f32x4){0.f, 0.f, 0.f, 0.f};

#pragma unroll
        for (int kc = 0; kc < 8; ++kc){
            short8 acur = *(const short8*)&hbuf[cur][kc * 32 + kq * 8];
#pragma unroll
            for (int g = 0; g < 3; ++g)
#pragma unroll
                for (int n = 0; n < 2; ++n)
                    acc[g][n] = __builtin_amdgcn_mfma_f32_16x16x32_bf16(acur, bf[g][n][kc], acc[g][n], 0, 0, 0);
        }

        int nxt = cur ^ 1;
        {
            float rr = sigm(b2f(ur0) + acc[0][0][0]);
            float zz = sigm(b2f(uz0) + acc[1][0][0]);
            float nn = tanh_(b2f(un0) + rr * (acc[2][0][0] + bhn[0]));
            float hv = nn + zz * (hold[0] - nn);
            hold[0] = hv;
            float rr1 = sigm(b2f(ur1) + acc[0][1][0]);
            float zz1 = sigm(b2f(uz1) + acc[1][1][0]);
            float nn1 = tanh_(b2f(un1) + rr1 * (acc[2][1][0] + bhn[1]));
            float hv1 = nn1 + zz1 * (hold[1] - nn1);
            hold[1] = hv1;
            if (kq == 0){
                unsigned short hb0 = f2b(hv), hb1 = f2b(hv1);
                hbuf[nxt][c0] = hb0;
                hbuf[nxt][c1] = hb1;
                oP[(size_t)(b * T + tt) * out_stride + c0] = hb0;
                oP[(size_t)(b * T + tt) * out_stride + c1] = hb1;
            }
        }
        __syncthreads();
        ur0 = vr0; ur1 = vr1; uz0 = vz0; uz1 = vz1; un0 = vn0; un1 = vn1;
        tt += tstep;
        cur = nxt;
    }
}

// ---------------------------------------------------------------------------
// sum(fwd,bwd) + LayerNorm -> bf16 rows
// ---------------------------------------------------------------------------
__global__ __launch_bounds__(256, 4) void sum_ln(
    const unsigned short* __restrict__ h1, const float* __restrict__ g,
    const float* __restrict__ bb, unsigned short* __restrict__ vn)
{
    int row = blockIdx.x * 4 + (threadIdx.x >> 6);
    int lane = threadIdx.x & 63;
    ushort4_t fa = *(const ushort4_t*)&h1[(size_t)row * 256 + lane * 4];
    ushort4_t ba = *(const ushort4_t*)&h1[8388608 + (size_t)row * 256 + lane * 4];
    float v[4]; float s = 0.f, q = 0.f;
#pragma unroll
    for (int k = 0; k < 4; ++k){
        v[k] = b2f(fa[k]) + b2f(ba[k]);
        s += v[k]; q += v[k] * v[k];
    }
#pragma unroll
    for (int o = 32; o; o >>= 1){
        s += __shfl_xor(s, o);
        q += __shfl_xor(q, o);
    }
    float mu = s * (1.f / 256.f);
    float var = q * (1.f / 256.f) - mu * mu;
    float rs = rsqrtf(var + 1e-5f);
    float4_t gg = *(const float4_t*)&g[lane * 4];
    float4_t bv = *(const float4_t*)&bb[lane * 4];
    ushort4_t o4;
#pragma unroll
    for (int k = 0; k < 4; ++k) o4[k] = f2b((v[k] - mu) * rs * gg[k] + bv[k]);
    *(ushort4_t*)&vn[(size_t)row * 256 + lane * 4] = o4;
}

// ---------------------------------------------------------------------------
extern "C" void kernel_launch(void* const* d_in, const int* in_sizes, int n_in,
                              void* d_out, int out_size, void* d_ws, size_t ws_size,
                              hipStream_t stream)
{
    (void)in_sizes; (void)n_in; (void)out_size; (void)ws_size;
    const float* x = (const float*)d_in[0];

    char* ws = (char*)d_ws;
    unsigned short* xT   = (unsigned short*)(ws);                 // 16 MB   (later reused as vn)
    unsigned short* giA  = (unsigned short*)(ws + 16777216);      // 100.7MB (gi0 -> gi1 -> hid)
    unsigned short* h0   = (unsigned short*)(ws + 117440512);     // 33.6 MB (h0out -> h1out)
    unsigned short* wbuf = (unsigned short*)(ws + 150994944);     // 4.5 MB bf16 weights
    float* out = (float*)d_out;

    // 1) cast weights to bf16
    CastArgs ca;
    ca.s[0] = (const float*)d_in[1];   // w_ih0f
    ca.s[1] = (const float*)d_in[2];   // w_hh0f
    ca.s[2] = (const float*)d_in[5];   // w_ih0b
    ca.s[3] = (const float*)d_in[6];   // w_hh0b
    ca.s[4] = (const float*)d_in[9];   // w_ih1f
    ca.s[5] = (const float*)d_in[10];  // w_hh1f
    ca.s[6] = (const float*)d_in[13];  // w_ih1b
    ca.s[7] = (const float*)d_in[14];  // w_hh1b
    ca.s[8] = (const float*)d_in[19];  // w1
    ca.s[9] = (const float*)d_in[21];  // w2
    cast_w<<<dim3(192, 10), 256, 0, stream>>>(ca, wbuf);

    // 2) transpose x -> xT bf16
    transpose_x<<<dim3(64, 8, 16), 256, 0, stream>>>(x, xT);

    // 3) layer-0 input gates: gi0[dir] = xT @ w_ih0d^T + b_ih0d + b_hh0d(r,z)
    gemm64<0><<<dim3(512, 12), 256, 0, stream>>>(xT, wbuf + 0,
        (const float*)d_in[3], (const float*)d_in[4], 512, giA, 256, 768);
    gemm64<0><<<dim3(512, 12), 256, 0, stream>>>(xT, wbuf + 393216,
        (const float*)d_in[7], (const float*)d_in[8], 512, giA + (size_t)25165824, 256, 768);

    // 4) layer-0 scan -> h0 [32768][512] (fwd cols 0-255, bwd 256-511)
    gru_scan<<<32, 512, 0, stream>>>(giA, wbuf + 196608, wbuf + 589824,
        (const float*)d_in[4], (const float*)d_in[8], h0, 512, (size_t)256);

    // 5) layer-1 input gates from h0 (K=512)
    gemm64<0><<<dim3(512, 12), 256, 0, stream>>>(h0, wbuf + 786432,
        (const float*)d_in[11], (const float*)d_in[12], 512, giA, 512, 768);
    gemm64<0><<<dim3(512, 12), 256, 0, stream>>>(h0, wbuf + 1376256,
        (const float*)d_in[15], (const float*)d_in[16], 512, giA + (size_t)25165824, 512, 768);

    // 6) layer-1 scan -> h0 reused as h1out [2][32768][256]
    gru_scan<<<32, 512, 0, stream>>>(giA, wbuf + 1179648, wbuf + 1769472,
        (const float*)d_in[12], (const float*)d_in[16], h0, 256, (size_t)8388608);

    // 7) sum dirs + LayerNorm -> vn (reuse xT)
    sum_ln<<<8192, 256, 0, stream>>>(h0, (const float*)d_in[17], (const float*)d_in[18], xT);

    // 8) FFN1: relu(vn @ w1^T + b1) -> hid (reuse giA)
    gemm64<1><<<dim3(512, 8), 256, 0, stream>>>(xT, wbuf + 1966080,
        (const float*)d_in[20], nullptr, 0, giA, 256, 512);

    // 9) FFN2: hid @ w2^T + b2 -> d_out f32, transposed to (B,C,L)
    gemm64_tr<<<dim3(512, 4), 256, 0, stream>>>(giA, wbuf + 2097152,
        (const float*)d_in[22], out, 512, 256);
}